// Round 5
// baseline (319.588 us; speedup 1.0000x reference)
//
#include <hip/hip_runtime.h>

// KAN Convolutional Layer, fp32, MI355X. Round 5.
// x (16,32,64,64) f32 -> out (16, 256, 62, 62) f32.
//
// R4 was latency-bound at 49% VALUBusy with only 3 blocks/CU (50.7KB LDS).
// Fix: basis features stored as bf16 packed into one uint4 per pixel
// (silu stays fp32 -> rounding impact negligible). LDS 50.7 -> 27.5KB ->
// 5 blocks/CU, 20 waves/CU for latency hiding. Conv reads per pixel-tap:
// 1x ds_read_b128 + 1x ds_read_b32; unpack = 1 shift/1 and per feature.

constexpr int Hh = 64, Ww = 64;
constexpr int Ho = 62, Wo = 62;
constexpr int L  = Ho * Wo;        // 3844
constexpr int NC = 8;              // n_convs
constexpr int RW  = 5;             // output rows per wave
constexpr int RPB = 20;            // 4 waves * 5 rows
constexpr int SR  = RPB + 2;       // staged input rows (max 22)
constexpr int NPX = SR * Ww;       // 1408
constexpr int NSTRIP = 4;

__global__ __launch_bounds__(128)
void fold_weights(const float* __restrict__ bw, const float* __restrict__ sw,
                  const float* __restrict__ scl, float* __restrict__ wf)
{
    // wf[k*72 + f*8 + n]: f=0 -> base_w, f=1..8 -> spline_w * scaler
    int i = threadIdx.x;
    if (i < 72) {
        const int n = i & 7;
        const int k = i >> 3;
        const int m = n * 9 + k;
        const float sc = scl[m];
        wf[k * 72 + 0 * 8 + n] = bw[m];
#pragma unroll
        for (int f = 1; f < 9; f++)
            wf[k * 72 + f * 8 + n] = sw[m * 8 + (f - 1)] * sc;
    }
}

__device__ __forceinline__ uint pack_bf16_pair(float lo, float hi) {
    // truncation rounding: error <= 2^-8 relative, negligible for basis values
    return (__float_as_uint(hi) & 0xffff0000u) | (__float_as_uint(lo) >> 16);
}

__global__ __launch_bounds__(256, 5)
void kan_conv_kernel(const float* __restrict__ x,
                     const float* __restrict__ wf,
                     float* __restrict__ out)
{
    __shared__ float ssh[NPX];       //  5632 B  silu (fp32)
    __shared__ uint4 bsh[NPX];       // 22528 B  basis f1..f8 as 8x bf16
                                     // total 28160 B -> 5 blocks/CU

    const int strip = blockIdx.x & (NSTRIP - 1);
    const int bc    = blockIdx.x >> 2;           // b*32 + c
    const int s0    = strip * RPB;

    // ---- feature stage ----
    const int stage_rows = (s0 + SR <= Hh) ? SR : (Hh - s0);
    const int npx = stage_rows * Ww;
    const float* xp = x + (size_t)bc * (Hh * Ww) + (size_t)s0 * Ww;

    for (int p = threadIdx.x; p < npx; p += 256) {
        const float v  = xp[p];
        ssh[p] = v / (1.0f + __expf(-v));        // silu, fp32

        // uniform cubic B-spline closed form; knots (i-3)*0.4-1 -> u=(v+2.2)*2.5
        const float u  = (v + 2.2f) * 2.5f;
        const float fj = floorf(u);
        const float t  = u - fj;
        const int   j  = (int)fj - 3;            // basis slot of tap w0
        const float om = 1.0f - t;
        const float t2 = t * t;
        const float w3 = t * t2 * (1.0f / 6.0f);
        const float w0 = om * om * om * (1.0f / 6.0f);
        const float w1 = fmaf(t2, fmaf(t, 0.5f, -1.0f), 2.0f / 3.0f);
        const float w2 = 1.0f - w0 - w1 - w3;

        float b[8];
#pragma unroll
        for (int s = 0; s < 8; s++) {
            float r = 0.0f;
            r = (j == s    ) ? w0 : r;
            r = (j == s - 1) ? w1 : r;
            r = (j == s - 2) ? w2 : r;
            r = (j == s - 3) ? w3 : r;
            b[s] = r;
        }
        bsh[p] = make_uint4(pack_bf16_pair(b[0], b[1]),
                            pack_bf16_pair(b[2], b[3]),
                            pack_bf16_pair(b[4], b[5]),
                            pack_bf16_pair(b[6], b[7]));
    }
    __syncthreads();

    // ---- conv stage: wave -> 5 output rows, lane -> column ----
    const int wv = threadIdx.x >> 6;
    const int ln = threadIdx.x & 63;
    const int rbase = wv * RW;

    if (ln < Wo && s0 + rbase < Ho) {
        float acc[RW][NC];
#pragma unroll
        for (int r = 0; r < RW; r++)
#pragma unroll
            for (int n = 0; n < NC; n++) acc[r][n] = 0.0f;

#pragma unroll 1                      // rolled: body well inside I-cache
        for (int k = 0; k < 9; k++) {
            const int kh = k / 3;
            const int kw = k - kh * 3;
            const float* __restrict__ w = wf + k * 72;   // wave-uniform -> SGPR

#pragma unroll
            for (int r = 0; r < RW; r++) {
                const int px = (rbase + r + kh) * Ww + ln + kw;
                const float f0 = ssh[px];
                const uint4 q  = bsh[px];

                float f[8];
                f[0] = __uint_as_float(q.x << 16);
                f[1] = __uint_as_float(q.x & 0xffff0000u);
                f[2] = __uint_as_float(q.y << 16);
                f[3] = __uint_as_float(q.y & 0xffff0000u);
                f[4] = __uint_as_float(q.z << 16);
                f[5] = __uint_as_float(q.z & 0xffff0000u);
                f[6] = __uint_as_float(q.w << 16);
                f[7] = __uint_as_float(q.w & 0xffff0000u);

#pragma unroll
                for (int n = 0; n < NC; n++) {
                    float a = acc[r][n];
                    a = fmaf(f0,   w[     n], a);
                    a = fmaf(f[0], w[ 8 + n], a);
                    a = fmaf(f[1], w[16 + n], a);
                    a = fmaf(f[2], w[24 + n], a);
                    a = fmaf(f[3], w[32 + n], a);
                    a = fmaf(f[4], w[40 + n], a);
                    a = fmaf(f[5], w[48 + n], a);
                    a = fmaf(f[6], w[56 + n], a);
                    a = fmaf(f[7], w[64 + n], a);
                    acc[r][n] = a;
                }
            }
        }

        // ---- stores: coalesced per (row, conv) plane ----
#pragma unroll
        for (int r = 0; r < RW; r++) {
            const int orow = s0 + rbase + r;
            if (orow < Ho) {
                const size_t ob = (size_t)bc * NC * L + (size_t)orow * Wo + ln;
#pragma unroll
                for (int n = 0; n < NC; n++) out[ob + (size_t)n * L] = acc[r][n];
            }
        }
    }
}

extern "C" void kernel_launch(void* const* d_in, const int* in_sizes, int n_in,
                              void* d_out, int out_size, void* d_ws, size_t ws_size,
                              hipStream_t stream) {
    const float* x   = (const float*)d_in[0];
    const float* bw  = (const float*)d_in[1];
    const float* sw  = (const float*)d_in[2];
    const float* scl = (const float*)d_in[3];
    float* wf  = (float*)d_ws;                 // 648 floats
    float* out = (float*)d_out;

    fold_weights<<<1, 128, 0, stream>>>(bw, sw, scl, wf);

    const int planes = in_sizes[0] / (Hh * Ww);   // 512
    dim3 grid(planes * NSTRIP);                   // 2048 blocks
    kan_conv_kernel<<<grid, 256, 0, stream>>>(x, wf, out);
}

// Round 6
// 115.861 us; speedup vs baseline: 2.7584x; 2.7584x over previous
//
#include <hip/hip_runtime.h>

// KAN Convolutional Layer, fp32, MI355X. Round 6.
// x (16,32,64,64) f32 -> out (16, 256, 62, 62) f32.
//
// R5 post-mortem: __launch_bounds__(256,5) capped VGPRs to 48 < ~75 live ->
// accumulator array spilled to scratch (WRITE_SIZE 62->658MB, 5x regression).
// R6: identical kernel, bound relaxed to (256,4) (128-VGPR budget, no spill).
// Occupancy is then LDS-limited: 28.2KB -> 5 blocks/CU = 20 waves/CU.

constexpr int Hh = 64, Ww = 64;
constexpr int Ho = 62, Wo = 62;
constexpr int L  = Ho * Wo;        // 3844
constexpr int NC = 8;              // n_convs
constexpr int RW  = 5;             // output rows per wave
constexpr int RPB = 20;            // 4 waves * 5 rows
constexpr int SR  = RPB + 2;       // staged input rows (max 22)
constexpr int NPX = SR * Ww;       // 1408
constexpr int NSTRIP = 4;

__global__ __launch_bounds__(128)
void fold_weights(const float* __restrict__ bw, const float* __restrict__ sw,
                  const float* __restrict__ scl, float* __restrict__ wf)
{
    // wf[k*72 + f*8 + n]: f=0 -> base_w, f=1..8 -> spline_w * scaler
    int i = threadIdx.x;
    if (i < 72) {
        const int n = i & 7;
        const int k = i >> 3;
        const int m = n * 9 + k;
        const float sc = scl[m];
        wf[k * 72 + 0 * 8 + n] = bw[m];
#pragma unroll
        for (int f = 1; f < 9; f++)
            wf[k * 72 + f * 8 + n] = sw[m * 8 + (f - 1)] * sc;
    }
}

__device__ __forceinline__ uint pack_bf16_pair(float lo, float hi) {
    // truncation rounding: error <= 2^-8 relative, negligible for basis values
    return (__float_as_uint(hi) & 0xffff0000u) | (__float_as_uint(lo) >> 16);
}

__global__ __launch_bounds__(256, 4)   // 128-VGPR budget: fits ~75 live, no spill
void kan_conv_kernel(const float* __restrict__ x,
                     const float* __restrict__ wf,
                     float* __restrict__ out)
{
    __shared__ float ssh[NPX];       //  5632 B  silu (fp32)
    __shared__ uint4 bsh[NPX];       // 22528 B  basis f1..f8 as 8x bf16
                                     // total 28160 B -> 5 blocks/CU

    const int strip = blockIdx.x & (NSTRIP - 1);
    const int bc    = blockIdx.x >> 2;           // b*32 + c
    const int s0    = strip * RPB;

    // ---- feature stage ----
    const int stage_rows = (s0 + SR <= Hh) ? SR : (Hh - s0);
    const int npx = stage_rows * Ww;
    const float* xp = x + (size_t)bc * (Hh * Ww) + (size_t)s0 * Ww;

    for (int p = threadIdx.x; p < npx; p += 256) {
        const float v  = xp[p];
        ssh[p] = v / (1.0f + __expf(-v));        // silu, fp32

        // uniform cubic B-spline closed form; knots (i-3)*0.4-1 -> u=(v+2.2)*2.5
        const float u  = (v + 2.2f) * 2.5f;
        const float fj = floorf(u);
        const float t  = u - fj;
        const int   j  = (int)fj - 3;            // basis slot of tap w0
        const float om = 1.0f - t;
        const float t2 = t * t;
        const float w3 = t * t2 * (1.0f / 6.0f);
        const float w0 = om * om * om * (1.0f / 6.0f);
        const float w1 = fmaf(t2, fmaf(t, 0.5f, -1.0f), 2.0f / 3.0f);
        const float w2 = 1.0f - w0 - w1 - w3;

        float b[8];
#pragma unroll
        for (int s = 0; s < 8; s++) {
            float r = 0.0f;
            r = (j == s    ) ? w0 : r;
            r = (j == s - 1) ? w1 : r;
            r = (j == s - 2) ? w2 : r;
            r = (j == s - 3) ? w3 : r;
            b[s] = r;
        }
        bsh[p] = make_uint4(pack_bf16_pair(b[0], b[1]),
                            pack_bf16_pair(b[2], b[3]),
                            pack_bf16_pair(b[4], b[5]),
                            pack_bf16_pair(b[6], b[7]));
    }
    __syncthreads();

    // ---- conv stage: wave -> 5 output rows, lane -> column ----
    const int wv = threadIdx.x >> 6;
    const int ln = threadIdx.x & 63;
    const int rbase = wv * RW;

    if (ln < Wo && s0 + rbase < Ho) {
        float acc[RW][NC];
#pragma unroll
        for (int r = 0; r < RW; r++)
#pragma unroll
            for (int n = 0; n < NC; n++) acc[r][n] = 0.0f;

#pragma unroll 1                      // rolled: body well inside I-cache
        for (int k = 0; k < 9; k++) {
            const int kh = k / 3;
            const int kw = k - kh * 3;
            const float* __restrict__ w = wf + k * 72;   // wave-uniform -> SGPR

#pragma unroll
            for (int r = 0; r < RW; r++) {
                const int px = (rbase + r + kh) * Ww + ln + kw;
                const float f0 = ssh[px];
                const uint4 q  = bsh[px];

                float f[8];
                f[0] = __uint_as_float(q.x << 16);
                f[1] = __uint_as_float(q.x & 0xffff0000u);
                f[2] = __uint_as_float(q.y << 16);
                f[3] = __uint_as_float(q.y & 0xffff0000u);
                f[4] = __uint_as_float(q.z << 16);
                f[5] = __uint_as_float(q.z & 0xffff0000u);
                f[6] = __uint_as_float(q.w << 16);
                f[7] = __uint_as_float(q.w & 0xffff0000u);

#pragma unroll
                for (int n = 0; n < NC; n++) {
                    float a = acc[r][n];
                    a = fmaf(f0,   w[     n], a);
                    a = fmaf(f[0], w[ 8 + n], a);
                    a = fmaf(f[1], w[16 + n], a);
                    a = fmaf(f[2], w[24 + n], a);
                    a = fmaf(f[3], w[32 + n], a);
                    a = fmaf(f[4], w[40 + n], a);
                    a = fmaf(f[5], w[48 + n], a);
                    a = fmaf(f[6], w[56 + n], a);
                    a = fmaf(f[7], w[64 + n], a);
                    acc[r][n] = a;
                }
            }
        }

        // ---- stores: coalesced per (row, conv) plane ----
#pragma unroll
        for (int r = 0; r < RW; r++) {
            const int orow = s0 + rbase + r;
            if (orow < Ho) {
                const size_t ob = (size_t)bc * NC * L + (size_t)orow * Wo + ln;
#pragma unroll
                for (int n = 0; n < NC; n++) out[ob + (size_t)n * L] = acc[r][n];
            }
        }
    }
}

extern "C" void kernel_launch(void* const* d_in, const int* in_sizes, int n_in,
                              void* d_out, int out_size, void* d_ws, size_t ws_size,
                              hipStream_t stream) {
    const float* x   = (const float*)d_in[0];
    const float* bw  = (const float*)d_in[1];
    const float* sw  = (const float*)d_in[2];
    const float* scl = (const float*)d_in[3];
    float* wf  = (float*)d_ws;                 // 648 floats
    float* out = (float*)d_out;

    fold_weights<<<1, 128, 0, stream>>>(bw, sw, scl, wf);

    const int planes = in_sizes[0] / (Hh * Ww);   // 512
    dim3 grid(planes * NSTRIP);                   // 2048 blocks
    kan_conv_kernel<<<grid, 256, 0, stream>>>(x, wf, out);
}

// Round 7
// 104.947 us; speedup vs baseline: 3.0452x; 1.1040x over previous
//
#include <hip/hip_runtime.h>

// KAN Convolutional Layer, fp32->bf16 MFMA, MI355X. Round 7.
// x (16,32,64,64) f32 -> out (16, 256, 62, 62) f32.
//
// R6 plateaued at the vector-ALU latency floor (53us, VALUBusy 51%, MfmaUtil 0).
// Rewrite as GEMM on the matrix pipe: per 16-location tile,
//   D[16 convs x 16 locs] += A[16 convs x K=160] * B[K=160 x 16 locs]
// with K = 9 taps x 16-slot per-pixel feature record [silu, b0..b7, 0 x7] (bf16).
// 5x mfma_f32_16x16x32_bf16 per tile; weights pre-baked in A-fragment lane
// layout (d_ws), loaded once per wave; features read as 1 ds_read_b128 per
// lane per mfma with XOR swizzle -> 2-way banks (free).
//
// Verified layouts (docs m89/m91/m118): A[m=lane&15][k=(lane>>4)*8+j],
// B[k=(lane>>4)*8+j][n=lane&15], C/D col=lane&15, row=(lane>>4)*4+reg.

typedef __attribute__((ext_vector_type(8))) short bf16x8;
typedef __attribute__((ext_vector_type(4))) float f32x4;

constexpr int Hh = 64, Ww = 64;
constexpr int Ho = 62, Wo = 62;
constexpr int L  = Ho * Wo;          // 3844
constexpr int NC = 8;
constexpr int RPB = 12;              // output rows per block
constexpr int SR  = RPB + 2;         // staged input rows (max 14)
constexpr int NSTRIP = 6;            // 6*12 = 72 >= 62
constexpr int NPX = SR * Ww;         // 896
constexpr int LDS_PX = NPX + 4;      // +4 px guard for col-overflow reads
constexpr int ZQ = LDS_PX * 2;       // uint4 index of zero-pad record

__global__ __launch_bounds__(64)
void fold_weights(const float* __restrict__ bw, const float* __restrict__ sw,
                  const float* __restrict__ scl, ushort* __restrict__ wf)
{
    // wf[(c*64 + lane)*8 + j] = bf16 of A[m=lane&15][k = c*32 + (lane>>4)*8 + j]
    // K layout: k = tap*16 + slot; slot0=base_w, slot1..8=spline_w*scaler, else 0.
    const int l = threadIdx.x;       // 0..63
    const int conv = l & 15;
    const int g = l >> 4;
    for (int c = 0; c < 5; c++) {
        const int tap = 2 * c + (g >> 1);        // taps 0..9 (9 = zero pad)
        for (int j = 0; j < 8; j++) {
            const int slot = (g & 1) * 8 + j;
            float v = 0.0f;
            if (conv < 8 && tap < 9) {
                const int m = conv * 9 + tap;
                if (slot == 0)      v = bw[m];
                else if (slot <= 8) v = sw[m * 8 + (slot - 1)] * scl[m];
            }
            wf[(c * 64 + l) * 8 + j] = (ushort)((__float_as_uint(v) + 0x8000u) >> 16);
        }
    }
}

__device__ __forceinline__ uint pk(float lo, float hi) {
    // round-half-up bf16 pack
    return ((__float_as_uint(lo) + 0x8000u) >> 16) |
           ((__float_as_uint(hi) + 0x8000u) & 0xffff0000u);
}

__global__ __launch_bounds__(256, 4)
void kan_conv_kernel(const float* __restrict__ x,
                     const ushort* __restrict__ wf,
                     float* __restrict__ out)
{
    // per-pixel 32B record as 2x uint4; halves XOR-swizzled by (p>>2)&1.
    __shared__ uint4 pix[LDS_PX * 2 + 2];        // 28832 B -> 5 blocks/CU

    const int strip = blockIdx.x % NSTRIP;
    const int bc    = blockIdx.x / NSTRIP;       // b*32 + c
    const int s0    = strip * RPB;

    // zero-pad record (read by chunk-4 upper lane groups)
    if (threadIdx.x < 2) pix[ZQ + threadIdx.x] = make_uint4(0, 0, 0, 0);

    // ---- feature stage ----
    const int stage_rows = (s0 + SR <= Hh) ? SR : (Hh - s0);
    const int npx = stage_rows * Ww;
    const float* xp = x + (size_t)bc * (Hh * Ww) + (size_t)s0 * Ww;

    for (int p = threadIdx.x; p < npx; p += 256) {
        const float v  = xp[p];
        const float sv = v / (1.0f + __expf(-v));        // silu

        // uniform cubic B-spline closed form; knots (i-3)*0.4-1 -> u=(v+2.2)*2.5
        const float u  = (v + 2.2f) * 2.5f;
        const float fj = floorf(u);
        const float t  = u - fj;
        const int   j  = (int)fj - 3;            // basis slot of tap w0
        const float om = 1.0f - t;
        const float t2 = t * t;
        const float w3 = t * t2 * (1.0f / 6.0f);
        const float w0 = om * om * om * (1.0f / 6.0f);
        const float w1 = fmaf(t2, fmaf(t, 0.5f, -1.0f), 2.0f / 3.0f);
        const float w2 = 1.0f - w0 - w1 - w3;

        float b[8];
#pragma unroll
        for (int s = 0; s < 8; s++) {
            float r = 0.0f;
            r = (j == s    ) ? w0 : r;
            r = (j == s - 1) ? w1 : r;
            r = (j == s - 2) ? w2 : r;
            r = (j == s - 3) ? w3 : r;
            b[s] = r;
        }

        const int sw_ = (p >> 2) & 1;
        pix[p * 2 + sw_]       = make_uint4(pk(sv, b[0]), pk(b[1], b[2]),
                                            pk(b[3], b[4]), pk(b[5], b[6]));
        pix[p * 2 + (1 - sw_)] = make_uint4(pk(b[7], 0.0f), 0u, 0u, 0u);
    }
    __syncthreads();

    // ---- MFMA conv stage ----
    const int wv = threadIdx.x >> 6;     // wave -> column tile (c0 = wv*16)
    const int l  = threadIdx.x & 63;
    const int g  = l >> 4;
    const int m  = l & 15;
    const int h  = g & 1;
    const int c0 = wv * 16;

    // A fragments (weights), 5 chunks x 8 bf16, coalesced global load
    bf16x8 wa[5];
    const uint4* wfv = (const uint4*)wf;
#pragma unroll
    for (int c = 0; c < 5; c++) {
        uint4 q = wfv[c * 64 + l];
        wa[c] = *(const bf16x8*)&q;
    }

    // per-lane tap pixel offsets per chunk (th*Ww + tw)
    int dtap[5];
#pragma unroll
    for (int c = 0; c < 5; c++) {
        int tap = 2 * c + (g >> 1);
        if (tap > 8) tap = 8;            // unused: g>=2 & c==4 reads zero-pad
        dtap[c] = (tap / 3) * Ww + (tap % 3);
    }

    const int nrt  = (s0 + RPB <= Ho) ? RPB : (Ho - s0);   // valid row tiles
    const int pcol = c0 + m;                               // B location column
    const char* pixb = (const char*)pix;

    for (int rl = 0; rl < nrt; rl++) {
        const int ptile = rl * Ww + pcol;
        f32x4 acc = {0.0f, 0.0f, 0.0f, 0.0f};
#pragma unroll
        for (int c = 0; c < 5; c++) {
            const int p = ptile + dtap[c];
            int addr = (p << 5) + ((((p >> 2) & 1) ^ h) << 4);
            if (c == 4 && g >= 2) addr = ZQ * 16;          // zero-pad record
            const bf16x8 bfrag = *(const bf16x8*)(pixb + addr);
            acc = __builtin_amdgcn_mfma_f32_16x16x32_bf16(wa[c], bfrag, acc, 0, 0, 0);
        }

        // stores: lane col=m -> location, rows g*4+r -> conv (g<2 real)
        if (g < 2 && pcol < Wo) {
            float* op = out + ((size_t)bc * NC + g * 4) * L
                            + (size_t)(s0 + rl) * Wo + pcol;
            op[0 * L] = acc.x;
            op[1 * L] = acc.y;
            op[2 * L] = acc.z;
            op[3 * L] = acc.w;
        }
    }
}

extern "C" void kernel_launch(void* const* d_in, const int* in_sizes, int n_in,
                              void* d_out, int out_size, void* d_ws, size_t ws_size,
                              hipStream_t stream) {
    const float* x   = (const float*)d_in[0];
    const float* bw  = (const float*)d_in[1];
    const float* sw  = (const float*)d_in[2];
    const float* scl = (const float*)d_in[3];
    ushort* wf = (ushort*)d_ws;                  // 5*64*8 bf16 = 5120 B
    float* out = (float*)d_out;

    fold_weights<<<1, 64, 0, stream>>>(bw, sw, scl, wf);

    const int planes = in_sizes[0] / (Hh * Ww);  // 512
    dim3 grid(planes * NSTRIP);                  // 3072 blocks
    kan_conv_kernel<<<grid, 256, 0, stream>>>(x, wf, out);
}

// Round 8
// 101.297 us; speedup vs baseline: 3.1549x; 1.0360x over previous
//
#include <hip/hip_runtime.h>

// KAN Convolutional Layer, bf16 MFMA, MI355X. Round 8.
// x (16,32,64,64) f32 -> out (16, 256, 62, 62) f32.
//
// R7 wasted half of each 16x16 MFMA (8 real convs in M=16). R8 row-pairing:
// D rows 0..7 = convs 0..7 at output row r, rows 8..15 = convs 0..7 at row
// r+1 (A rows 8..15 hold kh-shifted weights). Shared B spans a 4x3 tap grid:
// K = 12 taps x 16 slots = 192 -> 6 mfma_f32_16x16x32_bf16 per 2 output rows
// (vs 10), 40% fewer LDS reads, all lanes store.
//
// Fragment layouts (validated by R7 pass): A[m=lane&15][k=(lane>>4)*8+j],
// B[k=(lane>>4)*8+j][n=lane&15], C/D col=lane&15, row=(lane>>4)*4+reg.

typedef __attribute__((ext_vector_type(8))) short bf16x8;
typedef __attribute__((ext_vector_type(4))) float f32x4;

constexpr int Hh = 64, Ww = 64;
constexpr int Ho = 62, Wo = 62;
constexpr int L  = Ho * Wo;          // 3844
constexpr int NC = 8;
constexpr int RPB = 12;              // output rows per block (6 pairs)
constexpr int SR  = RPB + 2;         // staged input rows (max 14)
constexpr int NSTRIP = 6;            // 6*12 = 72 >= 62
constexpr int NPX = SR * Ww;         // 896
constexpr int LDS_PX = NPX + 4;      // +4 px guard for col-overflow reads

__global__ __launch_bounds__(64)
void fold_weights(const float* __restrict__ bw, const float* __restrict__ sw,
                  const float* __restrict__ scl, ushort* __restrict__ wf)
{
    // wf[(c*64 + lane)*8 + j] = bf16 of A[m=lane&15][k = c*32 + (lane>>4)*8 + j]
    // K: k = tap*16 + slot, tap = kh*3+kw over a 4x3 grid (kh 0..3).
    // m<8:  conv m,   kernel row kh    (valid kh<=2)
    // m>=8: conv m-8, kernel row kh-1  (valid kh>=1)  -> output row r+1
    const int l = threadIdx.x;       // 0..63
    const int m = l & 15;
    const int g = l >> 4;
    const int conv = m & 7;
    for (int c = 0; c < 6; c++) {
        const int tap = 2 * c + (g >> 1);        // 0..11
        const int kh  = tap / 3, kw = tap % 3;
        const int kh2 = (m < 8) ? kh : kh - 1;
        for (int j = 0; j < 8; j++) {
            const int slot = (g & 1) * 8 + j;
            float v = 0.0f;
            if (kh2 >= 0 && kh2 <= 2) {
                const int idx = conv * 9 + kh2 * 3 + kw;
                if (slot == 0)      v = bw[idx];
                else if (slot <= 8) v = sw[idx * 8 + (slot - 1)] * scl[idx];
            }
            wf[(c * 64 + l) * 8 + j] = (ushort)((__float_as_uint(v) + 0x8000u) >> 16);
        }
    }
}

__device__ __forceinline__ uint pk(float lo, float hi) {
    return ((__float_as_uint(lo) + 0x8000u) >> 16) |
           ((__float_as_uint(hi) + 0x8000u) & 0xffff0000u);
}

__global__ __launch_bounds__(256, 4)
void kan_conv_kernel(const float* __restrict__ x,
                     const ushort* __restrict__ wf,
                     float* __restrict__ out)
{
    // per-pixel 32B record (16 bf16: silu, b0..b7, 0...) as 2x uint4;
    // halves XOR-swizzled by (p>>2)&1.
    __shared__ uint4 pix[LDS_PX * 2];            // 28800 B -> 5 blocks/CU

    const int strip = blockIdx.x % NSTRIP;
    const int bc    = blockIdx.x / NSTRIP;       // b*32 + c
    const int s0    = strip * RPB;

    // ---- feature stage ----
    const int stage_rows = (s0 + SR <= Hh) ? SR : (Hh - s0);
    const int npx = stage_rows * Ww;
    const float* xp = x + (size_t)bc * (Hh * Ww) + (size_t)s0 * Ww;

    for (int p = threadIdx.x; p < npx; p += 256) {
        const float v  = xp[p];
        const float sv = v / (1.0f + __expf(-v));        // silu

        // uniform cubic B-spline closed form; knots (i-3)*0.4-1 -> u=(v+2.2)*2.5
        const float u  = (v + 2.2f) * 2.5f;
        const float fj = floorf(u);
        const float t  = u - fj;
        const int   j  = (int)fj - 3;            // basis slot of tap w0
        const float om = 1.0f - t;
        const float t2 = t * t;
        const float w3 = t * t2 * (1.0f / 6.0f);
        const float w0 = om * om * om * (1.0f / 6.0f);
        const float w1 = fmaf(t2, fmaf(t, 0.5f, -1.0f), 2.0f / 3.0f);
        const float w2 = 1.0f - w0 - w1 - w3;

        float b[8];
#pragma unroll
        for (int s = 0; s < 8; s++) {
            float r = 0.0f;
            r = (j == s    ) ? w0 : r;
            r = (j == s - 1) ? w1 : r;
            r = (j == s - 2) ? w2 : r;
            r = (j == s - 3) ? w3 : r;
            b[s] = r;
        }

        const int sw_ = (p >> 2) & 1;
        pix[p * 2 + sw_]       = make_uint4(pk(sv, b[0]), pk(b[1], b[2]),
                                            pk(b[3], b[4]), pk(b[5], b[6]));
        pix[p * 2 + (1 - sw_)] = make_uint4(pk(b[7], 0.0f), 0u, 0u, 0u);
    }
    __syncthreads();

    // ---- MFMA conv stage ----
    const int wv = threadIdx.x >> 6;     // wave -> column tile
    const int l  = threadIdx.x & 63;
    const int g  = l >> 4;
    const int m  = l & 15;
    const int h  = g & 1;
    const int pcol = wv * 16 + m;        // B location column

    // A fragments (weights), 6 chunks x 8 bf16, coalesced global load
    bf16x8 wa[6];
    const uint4* wfv = (const uint4*)wf;
#pragma unroll
    for (int c = 0; c < 6; c++) {
        uint4 q = wfv[c * 64 + l];
        wa[c] = *(const bf16x8*)&q;
    }

    // per-lane tap pixel offsets per chunk
    int dtap[6];
#pragma unroll
    for (int c = 0; c < 6; c++) {
        const int tap = 2 * c + (g >> 1);        // 0..11
        dtap[c] = (tap / 3) * Ww + (tap % 3);
    }

    const int nrt = (s0 + RPB <= Ho) ? RPB : (Ho - s0);   // 12 or 2 (even)
    const char* pixb = (const char*)pix;
    const int rowoff = g >> 1;           // D rows 8..15 -> output row +1
    const int cbase  = (g & 1) * 4;      // D row within pair -> conv base

    for (int rl = 0; rl < nrt; rl += 2) {
        const int ptile = rl * Ww + pcol;
        f32x4 acc = {0.0f, 0.0f, 0.0f, 0.0f};
#pragma unroll
        for (int c = 0; c < 6; c++) {
            const int p = ptile + dtap[c];
            const int addr = (p << 5) + ((((p >> 2) & 1) ^ h) << 4);
            const bf16x8 bfrag = *(const bf16x8*)(pixb + addr);
            acc = __builtin_amdgcn_mfma_f32_16x16x32_bf16(wa[c], bfrag, acc, 0, 0, 0);
        }

        if (pcol < Wo) {
            float* op = out + ((size_t)bc * NC + cbase) * L
                            + (size_t)(s0 + rl + rowoff) * Wo + pcol;
            op[0 * L] = acc.x;
            op[1 * L] = acc.y;
            op[2 * L] = acc.z;
            op[3 * L] = acc.w;
        }
    }
}

extern "C" void kernel_launch(void* const* d_in, const int* in_sizes, int n_in,
                              void* d_out, int out_size, void* d_ws, size_t ws_size,
                              hipStream_t stream) {
    const float* x   = (const float*)d_in[0];
    const float* bw  = (const float*)d_in[1];
    const float* sw  = (const float*)d_in[2];
    const float* scl = (const float*)d_in[3];
    ushort* wf = (ushort*)d_ws;                  // 6*64*8 bf16 = 6144 B
    float* out = (float*)d_out;

    fold_weights<<<1, 64, 0, stream>>>(bw, sw, scl, wf);

    const int planes = in_sizes[0] / (Hh * Ww);  // 512
    dim3 grid(planes * NSTRIP);                  // 3072 blocks
    kan_conv_kernel<<<grid, 256, 0, stream>>>(x, wf, out);
}